// Round 6
// baseline (238.084 us; speedup 1.0000x reference)
//
#include <hip/hip_runtime.h>
#include <hip/hip_cooperative_groups.h>

namespace cg = cooperative_groups;

// Problem dims
#define Bb 8
#define Gg 512
#define Kk 64
#define Nn 1024
#define Mm 128
#define KM 8192           // Kk*Mm
#define GPB 16            // g per block in z-pass
#define NCH 32            // Gg/GPB partial chunks

struct Args {
  const float *z, *hs_grid, *hs_key, *z1w;
  const float *wsrc[7];            // wra,wrh,wla,wlh,wcR,wcl,kR (row-major originals)
  const float *wcR_w, *wcl_b;
  const float *hs_rec;
  const int   *mask;
  const float *wRl;
  const float *wra_b, *wrh_b, *wla_b, *wlh_b, *kR_b, *lig_rep;
  const float *mapL_w, *mapL_b, *fin_w, *fin_b;
  float *wT, *ra, *att, *laNum, *laDen, *la;
  float *attlP, *attrPM, *attrPS, *att_r, *Lk, *scores;
  float *pmT, *psT, *uP, *w1P, *w2P, *w0P, *v1, *v2, *sAv;
  float *out;
};

// ===========================================================================
// ONE cooperative kernel, 5 phases separated by grid.sync().
// grid = 256 blocks x 1024 threads; LDS 73.7 KB; launch_bounds caps VGPR<=128
// so one block/CU always fits -> 256 blocks co-resident guaranteed.
// ===========================================================================
__global__ __launch_bounds__(1024) void fused(Args a) {
  cg::grid_group grid = cg::this_grid();
  __shared__ __align__(16) float smem[18432];   // 73728 B
  const int bid = blockIdx.x;
  const int t = threadIdx.x;

  // ===================== P0: z-pass (all 256 blocks) =====================
  {
    float* s_hskey  = smem;            // 8192
    float* s_hsgrid = smem + 8192;     // 2048
    float* s_rn     = smem + 10240;    // 2 x 2048 (double buffered)
    float* s_rd     = smem + 14336;    // 2 x 2048

    const int b = bid >> 5;
    const int gblk = bid & 31;
    const int lane_m = t & 31;
    const int m4 = lane_m << 2;
    const int kgrp = t >> 5;           // 0..31
    const int wv = t >> 6;             // 0..15

    const float* hkb = a.hs_key + (size_t)b * KM;
    for (int idx = t; idx < KM; idx += 1024) s_hskey[idx] = hkb[idx];
    const float* hgb = a.hs_grid + ((size_t)b * Gg + gblk * GPB) * Mm;
    for (int idx = t; idx < GPB * Mm; idx += 1024) s_hsgrid[idx] = hgb[idx];

    const float zw0 = a.z1w[m4], zw1 = a.z1w[m4 + 1], zw2 = a.z1w[m4 + 2], zw3 = a.z1w[m4 + 3];

    float la_n[2][4], la_d[2][4];
#pragma unroll
    for (int i = 0; i < 2; ++i)
#pragma unroll
      for (int j = 0; j < 4; ++j) { la_n[i][j] = 0.f; la_d[i][j] = 0.f; }

    const float* zb = a.z + ((size_t)b * Gg + gblk * GPB) * (size_t)KM;
    const int ofs0 = (kgrp * 2) * Mm + m4;
    const int ofs1 = ofs0 + Mm;
    float4 c0 = *reinterpret_cast<const float4*>(zb + ofs0);
    float4 c1 = *reinterpret_cast<const float4*>(zb + ofs1);

    __syncthreads();   // staging ready

    for (int gl = 0; gl < GPB; ++gl) {
      float4 n0 = c0, n1 = c1;
      if (gl < GPB - 1) {
        n0 = *reinterpret_cast<const float4*>(zb + (size_t)(gl + 1) * KM + ofs0);
        n1 = *reinterpret_cast<const float4*>(zb + (size_t)(gl + 1) * KM + ofs1);
      }
      const int g = gblk * GPB + gl;
      const float4 hg = *reinterpret_cast<const float4*>(s_hsgrid + gl * Mm + m4);
      float rn0 = 0, rn1 = 0, rn2 = 0, rn3 = 0, rd0 = 0, rd1 = 0, rd2 = 0, rd3 = 0;
#pragma unroll
      for (int i = 0; i < 2; ++i) {
        const float4 v = (i == 0) ? c0 : c1;
        const int k = kgrp * 2 + i;
        const float e0 = __expf(v.x), e1 = __expf(v.y), e2 = __expf(v.z), e3 = __expf(v.w);
        la_n[i][0] += e0 * hg.x; la_n[i][1] += e1 * hg.y; la_n[i][2] += e2 * hg.z; la_n[i][3] += e3 * hg.w;
        la_d[i][0] += e0;        la_d[i][1] += e1;        la_d[i][2] += e2;        la_d[i][3] += e3;
        const float4 hk = *reinterpret_cast<const float4*>(s_hskey + k * Mm + m4);
        rn0 += e0 * hk.x; rn1 += e1 * hk.y; rn2 += e2 * hk.z; rn3 += e3 * hk.w;
        rd0 += e0; rd1 += e1; rd2 += e2; rd3 += e3;
        float ap = v.x * zw0 + v.y * zw1 + v.z * zw2 + v.w * zw3;
        ap += __shfl_xor(ap, 16); ap += __shfl_xor(ap, 8); ap += __shfl_xor(ap, 4);
        ap += __shfl_xor(ap, 2);  ap += __shfl_xor(ap, 1);
        if (lane_m == 0) a.att[((size_t)b * Gg + g) * Kk + k] = ap;
      }
      rn0 += __shfl_xor(rn0, 32); rn1 += __shfl_xor(rn1, 32); rn2 += __shfl_xor(rn2, 32); rn3 += __shfl_xor(rn3, 32);
      rd0 += __shfl_xor(rd0, 32); rd1 += __shfl_xor(rd1, 32); rd2 += __shfl_xor(rd2, 32); rd3 += __shfl_xor(rd3, 32);
      float* rnB = s_rn + (gl & 1) * 2048;
      float* rdB = s_rd + (gl & 1) * 2048;
      if ((t & 63) < 32) {
        *reinterpret_cast<float4*>(rnB + wv * Mm + m4) = make_float4(rn0, rn1, rn2, rn3);
        *reinterpret_cast<float4*>(rdB + wv * Mm + m4) = make_float4(rd0, rd1, rd2, rd3);
      }
      __syncthreads();
      if (t < Mm) {
        float num = 0.f, den = 0.f;
#pragma unroll
        for (int ww = 0; ww < 16; ++ww) { num += rnB[ww * Mm + t]; den += rdB[ww * Mm + t]; }
        a.ra[((size_t)b * Gg + g) * Mm + t] = num / den;
      }
      c0 = n0; c1 = n1;
    }

    const size_t base = ((size_t)(b * NCH + gblk)) * KM;
#pragma unroll
    for (int i = 0; i < 2; ++i) {
      const int k = kgrp * 2 + i;
      *reinterpret_cast<float4*>(a.laNum + base + k * Mm + m4) =
          make_float4(la_n[i][0], la_n[i][1], la_n[i][2], la_n[i][3]);
      *reinterpret_cast<float4*>(a.laDen + base + k * Mm + m4) =
          make_float4(la_d[i][0], la_d[i][1], la_d[i][2], la_d[i][3]);
    }
  }
  __syncthreads();
  // ---- weight transpose epilogue: blocks 0..111, 32x32 tiles ----
  if (bid < 112) {
    float* tile = smem;                           // 32*33
    const int mat = bid >> 4, tl = bid & 15;
    const int xo = (tl & 3) * 32, y0 = (tl >> 2) * 32;
    const int tx = t & 31, ty = t >> 5;           // 32 x 32
    const float* src = a.wsrc[mat];
    float* dst = a.wT + (size_t)mat * Mm * Mm;
    tile[ty * 33 + tx] = src[(size_t)(y0 + ty) * Mm + xo + tx];
    __syncthreads();
    dst[(size_t)(xo + ty) * Mm + y0 + tx] = tile[tx * 33 + ty];
  }
  grid.sync();

  // ===================== P1: la-reduce | att_l | att_r partials | Lk ======
  // 448 virtual blocks of 256 threads, 4 per real block -> 112 real blocks
  if (bid < 112) {
    const int vb = (bid << 2) | (t >> 8);
    const int vt = t & 255;
    float* smp = smem + (t >> 8) * 1088;
    if (vb < 256) {
      // ---- la = sum(num)/sum(den) over 32 chunks ----
      const int idx = vb * 256 + vt;
      const int b = idx >> 13, r = idx & 8191;
      const float* np = a.laNum + (size_t)b * NCH * KM + r;
      const float* dp = a.laDen + (size_t)b * NCH * KM + r;
      float num = 0.f, den = 0.f;
#pragma unroll 8
      for (int p = 0; p < NCH; ++p) { num += np[(size_t)p * KM]; den += dp[(size_t)p * KM]; }
      a.la[idx] = num / den;
    } else if (vb < 320) {
      // ---- att_l partials ----
      const int blk = vb - 256;
      const int b = blk >> 3, p = blk & 7;
      const int w = vt >> 6, lane = vt & 63;
      float acc = 0.f;
      for (int j = 0; j < 16; ++j) {
        const int g = p * 64 + w * 16 + j;
        const float av = a.att[((size_t)b * Gg + g) * Kk + lane];
        float mx = av;
        for (int off = 32; off; off >>= 1) mx = fmaxf(mx, __shfl_xor(mx, off));
        const float e = __expf(av - mx);
        float s = e;
        for (int off = 32; off; off >>= 1) s += __shfl_xor(s, off);
        acc += e / s;
      }
      smp[w * 64 + lane] = acc;
      __syncthreads();
      if (vt < 64) a.attlP[(b * 8 + p) * 64 + vt] = smp[vt] + smp[64 + vt] + smp[128 + vt] + smp[192 + vt];
    } else if (vb < 384) {
      // ---- att_r online max/sum partials ----
      const int blk = vb - 320;
      const int b = blk >> 3, gc = blk & 7;
      const int k = vt & 63, j4 = vt >> 6;
      float m = -1e30f, s = 0.f;
      for (int j = 0; j < 16; ++j) {
        const int g = gc * 64 + j4 * 16 + j;
        const float av = a.att[((size_t)b * Gg + g) * Kk + k];
        if (av > m) { s = s * __expf(m - av) + 1.0f; m = av; }
        else s += __expf(av - m);
      }
      float* sm = smp;           // 256
      float* ss = smp + 256;     // 256
      sm[j4 * 64 + k] = m; ss[j4 * 64 + k] = s;
      __syncthreads();
      if (vt < 64) {
        float M = sm[vt];
        for (int q = 1; q < 4; ++q) M = fmaxf(M, sm[q * 64 + vt]);
        float S = 0.f;
        for (int q = 0; q < 4; ++q) S += ss[q * 64 + vt] * __expf(sm[q * 64 + vt] - M);
        a.attrPM[(b * 8 + gc) * 64 + vt] = M;
        a.attrPS[(b * 8 + gc) * 64 + vt] = S;
      }
    } else {
      // ---- Lk chain: lh = key@wclT + bl ; Lk[k,h] = sum_m lh[k,m]*wcR[m,h]
      const int blk = vb - 384;
      const int b = blk >> 3, k8 = blk & 7;
      float* s_lh = smp;                 // 8 x 132 = 1056
      const int m = vt & 127;
      const int half = __builtin_amdgcn_readfirstlane(vt >> 7);
      const float* wclT = a.wT + 5 * 16384;
      {
        const float* keyb = a.hs_key + ((size_t)b * Kk + k8 * 8 + half * 4) * Mm;  // wave-uniform
        float a0 = 0.f, a1 = 0.f, a2 = 0.f, a3 = 0.f;
        for (int h = 0; h < 128; ++h) {
          const float w = wclT[(size_t)h * Mm + m];
          const float r0v = keyb[h];
          const float r1v = keyb[128 + h];
          const float r2v = keyb[256 + h];
          const float r3v = keyb[384 + h];
          a0 += r0v * w; a1 += r1v * w; a2 += r2v * w; a3 += r3v * w;
        }
        const float bm = a.wcl_b[m];
        s_lh[(half * 4 + 0) * 132 + m] = a0 + bm;
        s_lh[(half * 4 + 1) * 132 + m] = a1 + bm;
        s_lh[(half * 4 + 2) * 132 + m] = a2 + bm;
        s_lh[(half * 4 + 3) * 132 + m] = a3 + bm;
      }
      __syncthreads();
      {
        const int h = m;
        const int r0 = half * 4;
        float b0 = 0.f, b1 = 0.f, b2 = 0.f, b3 = 0.f;
        for (int mq = 0; mq < 32; ++mq) {
          const float4 L0 = *reinterpret_cast<const float4*>(&s_lh[(r0 + 0) * 132 + mq * 4]);
          const float4 L1 = *reinterpret_cast<const float4*>(&s_lh[(r0 + 1) * 132 + mq * 4]);
          const float4 L2 = *reinterpret_cast<const float4*>(&s_lh[(r0 + 2) * 132 + mq * 4]);
          const float4 L3 = *reinterpret_cast<const float4*>(&s_lh[(r0 + 3) * 132 + mq * 4]);
          const float w0 = a.wcR_w[(size_t)(mq * 4 + 0) * Mm + h];
          const float w1 = a.wcR_w[(size_t)(mq * 4 + 1) * Mm + h];
          const float w2 = a.wcR_w[(size_t)(mq * 4 + 2) * Mm + h];
          const float w3 = a.wcR_w[(size_t)(mq * 4 + 3) * Mm + h];
          b0 += L0.x * w0 + L0.y * w1 + L0.z * w2 + L0.w * w3;
          b1 += L1.x * w0 + L1.y * w1 + L1.z * w2 + L1.w * w3;
          b2 += L2.x * w0 + L2.y * w1 + L2.z * w2 + L2.w * w3;
          b3 += L3.x * w0 + L3.y * w1 + L3.z * w2 + L3.w * w3;
        }
        const size_t ob = ((size_t)b * Kk + k8 * 8 + r0) * Mm + h;
        a.Lk[ob] = b0; a.Lk[ob + Mm] = b1; a.Lk[ob + 2 * Mm] = b2; a.Lk[ob + 3 * Mm] = b3;
      }
    }
  }
  grid.sync();

  // ===================== P2: att_r final | scores + softmax partials ======
  // 576 virtual blocks of 256 threads -> 144 real blocks
  if (bid < 144) {
    const int vb = (bid << 2) | (t >> 8);
    const int vt = t & 255;
    float* smp = smem + (t >> 8) * 4608;
    if (vb < 64) {
      const int b = vb >> 3, gc = vb & 7;
      const int k = vt & 63, grp = vt >> 6;
      float* Mx = smp;
      float* S = smp + 64;
      if (vt < 64) {
        float M = -1e30f;
        for (int p = 0; p < 8; ++p) M = fmaxf(M, a.attrPM[(b * 8 + p) * 64 + vt]);
        float s = 0.f;
        for (int p = 0; p < 8; ++p) s += a.attrPS[(b * 8 + p) * 64 + vt] * __expf(a.attrPM[(b * 8 + p) * 64 + vt] - M);
        Mx[vt] = M; S[vt] = s;
      }
      __syncthreads();
      const float Mk = Mx[k], Sk = S[k];
      for (int j = 0; j < 16; ++j) {
        const int g = gc * 64 + grp * 16 + j;
        float p = __expf(a.att[((size_t)b * Gg + g) * Kk + k] - Mk) / Sk;
        for (int off = 32; off; off >>= 1) p += __shfl_xor(p, off);
        if (k == 0) a.att_r[b * Gg + g] = p;
      }
      __syncthreads();   // match barrier count with scores path? not needed: per-real-block uniform type
    } else {
      const int vbs = vb - 64;
      const int b = vbs >> 6, ntile = vbs & 63;
      const int n0 = ntile * 16;
      const int k = vt & 63;
      const int hq = __builtin_amdgcn_readfirstlane(vt >> 6);
      float rLk[32];
      {
        const float* Lp = a.Lk + ((size_t)b * Kk + k) * Mm + hq * 32;
#pragma unroll
        for (int j = 0; j < 8; ++j) {
          const float4 v = *reinterpret_cast<const float4*>(Lp + j * 4);
          rLk[j * 4 + 0] = v.x; rLk[j * 4 + 1] = v.y;
          rLk[j * 4 + 2] = v.z; rLk[j * 4 + 3] = v.w;
        }
      }
      float acc[16];
      const float* rb = a.hs_rec + ((size_t)b * Nn + n0) * Mm + hq * 32;  // wave-uniform
#pragma unroll
      for (int r = 0; r < 16; ++r) {
        const float* rp = rb + r * Mm;
        float s = 0.f;
#pragma unroll
        for (int j = 0; j < 32; ++j) s += rp[j] * rLk[j];
        acc[r] = s;
      }
      float* s_acc = smp;          // 4096
      float* s_m   = smp + 4096;   // 256
      float* s_s   = smp + 4352;   // 256
#pragma unroll
      for (int r = 0; r < 16; ++r) s_acc[(hq * 16 + r) * 64 + k] = acc[r];
      __syncthreads();
      const float wv = a.wRl[0];
      const bool msk = (a.mask[b * Kk + k] == 0);
      float m = -3.0e38f, ssum = 0.f;
      for (int q = 0; q < 4; ++q) {
        const int idx = q * 256 + vt;
        const int r = idx >> 6, kk = idx & 63;
        float v = s_acc[r * 64 + kk] + s_acc[(16 + r) * 64 + kk] +
                  s_acc[(32 + r) * 64 + kk] + s_acc[(48 + r) * 64 + kk];
        v = msk ? -1e10f : wv * v;
        a.scores[((size_t)b * Nn + n0 + r) * Kk + kk] = v;
        if (v > m) { ssum = ssum * __expf(m - v) + 1.0f; m = v; }
        else ssum += __expf(v - m);
      }
      s_m[hq * 64 + k] = m; s_s[hq * 64 + k] = ssum;
      __syncthreads();
      if (vt < 64) {
        float M = fmaxf(fmaxf(s_m[vt], s_m[64 + vt]), fmaxf(s_m[128 + vt], s_m[192 + vt]));
        float S = 0.f;
#pragma unroll
        for (int q = 0; q < 4; ++q) S += s_s[q * 64 + vt] * __expf(s_m[q * 64 + vt] - M);
        a.pmT[((size_t)b * 64 + ntile) * 64 + vt] = M;
        a.psT[((size_t)b * 64 + ntile) * 64 + vt] = S;
      }
    }
  }
  grid.sync();

  // ===================== P3: weighted-sum partial reductions ==============
  // 136 virtual blocks of 512 threads -> 68 real blocks
  if (bid < 68) {
    const int vb = (bid << 1) | (t >> 9);
    const int vt = t & 511;
    float* smp = smem + (t >> 9) * 1472;
    float* sm = smp;                 // 1280
    float* s_attl = smp + 1280;      // 64
    float* sM = smp + 1344;          // 64
    float* sSi = smp + 1408;         // 64
    if (vb < 64) {
      const int b = vb >> 3, nc = vb & 7;
      if (vt < 64) {
        float aa = 0.f;
        for (int p = 0; p < 8; ++p) aa += a.attlP[(b * 8 + p) * 64 + vt];
        s_attl[vt] = aa;
        float M = -3.0e38f;
        for (int nt = 0; nt < 64; ++nt) M = fmaxf(M, a.pmT[((size_t)b * 64 + nt) * 64 + vt]);
        float S = 0.f;
        for (int nt = 0; nt < 64; ++nt)
          S += a.psT[((size_t)b * 64 + nt) * 64 + vt] * __expf(a.pmT[((size_t)b * 64 + nt) * 64 + vt] - M);
        sM[vt] = M; sSi[vt] = 1.0f / S;
      }
      __syncthreads();
      const int n = vt >> 2, ks = vt & 3;
      const float* sc = a.scores + ((size_t)b * Nn + nc * 128 + n) * Kk + ks * 16;
      float qp = 0.f;
#pragma unroll
      for (int j = 0; j < 16; ++j) {
        const int k = ks * 16 + j;
        qp += s_attl[k] * __expf(sc[j] - sM[k]) * sSi[k];
      }
      sm[n * 4 + ks] = qp;
      __syncthreads();
      float* q = sm + 512;
      if (vt < 128) q[vt] = sm[vt * 4] + sm[vt * 4 + 1] + sm[vt * 4 + 2] + sm[vt * 4 + 3];
      __syncthreads();
      const int h = vt & 127, nq = vt >> 7;
      float acc = 0.f;
      const float* hr = a.hs_rec + ((size_t)b * Nn + nc * 128 + nq * 32) * Mm + h;
      for (int j = 0; j < 32; ++j) acc += q[nq * 32 + j] * hr[(size_t)j * Mm];
      float* red = sm + 640;
      red[nq * 128 + h] = acc;
      __syncthreads();
      if (vt < 128) a.uP[((size_t)b * 8 + nc) * 128 + vt] = red[vt] + red[128 + vt] + red[256 + vt] + red[384 + vt];
    } else if (vb < 128) {
      const int blk = vb - 64;
      const int b = blk >> 3, gc = blk & 7;
      float* s_ar = sm + 1152;   // 64
      if (vt < 64) s_ar[vt] = a.att_r[b * Gg + gc * 64 + vt];
      __syncthreads();
      const int h = vt & 127, gq = vt >> 7;
      float a1 = 0.f, a2 = 0.f;
      const float* rp = a.ra + ((size_t)b * Gg + gc * 64 + gq * 16) * Mm + h;
      const float* gp = a.hs_grid + ((size_t)b * Gg + gc * 64 + gq * 16) * Mm + h;
      for (int j = 0; j < 16; ++j) {
        const float w = s_ar[gq * 16 + j];
        a1 += w * rp[(size_t)j * Mm];
        a2 += w * gp[(size_t)j * Mm];
      }
      float* r1 = sm;
      float* r2 = sm + 512;
      r1[gq * 128 + h] = a1; r2[gq * 128 + h] = a2;
      __syncthreads();
      if (vt < 128) {
        a.w1P[((size_t)b * 8 + gc) * 128 + vt] = r1[vt] + r1[128 + vt] + r1[256 + vt] + r1[384 + vt];
        a.w2P[((size_t)b * 8 + gc) * 128 + vt] = r2[vt] + r2[128 + vt] + r2[256 + vt] + r2[384 + vt];
      }
      if (vt == 0) {
        float s = 0.f;
        for (int j = 0; j < 64; ++j) s += s_ar[j];
        a.w0P[b * 8 + gc] = s;
      }
    } else {
      const int b = vb - 128;
      if (vt < 64) {
        float aa = 0.f;
        for (int p = 0; p < 8; ++p) aa += a.attlP[(b * 8 + p) * 64 + vt];
        s_attl[vt] = aa;
      }
      __syncthreads();
      const int h = vt & 127, kq = vt >> 7;
      float a1 = 0.f, a2 = 0.f;
      const float* lp = a.la + ((size_t)b * Kk + kq * 16) * Mm + h;
      const float* kp = a.hs_key + ((size_t)b * Kk + kq * 16) * Mm + h;
      for (int j = 0; j < 16; ++j) {
        const float w = s_attl[kq * 16 + j];
        a1 += w * lp[(size_t)j * Mm];
        a2 += w * kp[(size_t)j * Mm];
      }
      float* r1 = sm;
      float* r2 = sm + 512;
      r1[kq * 128 + h] = a1; r2[kq * 128 + h] = a2;
      __syncthreads();
      if (vt < 128) {
        a.v1[b * 128 + vt] = r1[vt] + r1[128 + vt] + r1[256 + vt] + r1[384 + vt];
        a.v2[b * 128 + vt] = r2[vt] + r2[128 + vt] + r2[256 + vt] + r2[384 + vt];
      }
      if (vt == 0) {
        float s = 0.f;
        for (int j = 0; j < 64; ++j) s += s_attl[j];
        a.sAv[b] = s;
      }
    }
  }
  grid.sync();

  // ===================== P4: finale (8 virtual blocks of 256) =============
  if (bid < 2) {
    const int vb = (bid << 2) | (t >> 8);   // = b
    const int vt = t & 255;
    float* smp = smem + (t >> 8) * 1440;
    float* sV1 = smp;          float* sV2 = smp + 128;
    float* sU  = smp + 256;    float* sW1 = smp + 384;  float* sW2 = smp + 512;
    float* sPair = smp + 640;  // 264
    float* sRed  = smp + 904;  // 2*2*128 = 512
    float* s5    = smp + 1416; // 8
    float* sSc   = smp + 1424; // 2
    const int b = vb;
    const int m = vt & 127, hf = vt >> 7;

    if (vt < 128) {
      float u = 0.f, w1 = 0.f, w2 = 0.f;
      for (int c = 0; c < 8; ++c) {
        u  += a.uP[((size_t)b * 8 + c) * 128 + vt];
        w1 += a.w1P[((size_t)b * 8 + c) * 128 + vt];
        w2 += a.w2P[((size_t)b * 8 + c) * 128 + vt];
      }
      sU[vt] = u; sW1[vt] = w1; sW2[vt] = w2;
      sV1[vt] = a.v1[b * 128 + vt]; sV2[vt] = a.v2[b * 128 + vt];
    }
    if (vt == 0) {
      float s = 0.f;
      for (int c = 0; c < 8; ++c) s += a.w0P[b * 8 + c];
      sSc[0] = s;            // sR
      sSc[1] = a.sAv[b];     // sA
    }
    __syncthreads();

    const float* wraT = a.wT;
    const float* wrhT = a.wT + 1 * 16384;
    const float* wlaT = a.wT + 2 * 16384;
    const float* wlhT = a.wT + 3 * 16384;
    const float* kRT  = a.wT + 6 * 16384;
    float key = 0.f, grd = 0.f;
    for (int h = hf * 64; h < hf * 64 + 64; ++h) {
      key += sV1[h] * wlaT[h * Mm + m] + sV2[h] * wlhT[h * Mm + m] + sU[h] * kRT[h * Mm + m];
      grd += sW1[h] * wraT[h * Mm + m] + sW2[h] * wrhT[h * Mm + m];
    }
    sRed[0 * 256 + hf * 128 + m] = key;
    sRed[1 * 256 + hf * 128 + m] = grd;
    __syncthreads();
    if (vt < 128) {
      const float sR = sSc[0], sA = sSc[1];
      sPair[vt] = sRed[vt] + sRed[128 + vt] + sA * (a.wla_b[vt] + a.wlh_b[vt] + a.kR_b[vt]);
      sPair[132 + vt] = sRed[256 + vt] + sRed[384 + vt] + sR * (a.wra_b[vt] + a.wrh_b[vt]);
    }
    if (vt < 4) sPair[128 + vt] = a.lig_rep[b * 4 + vt];
    __syncthreads();

    const int wq = vt >> 6, lane = vt & 63;
    for (int l = wq; l < 5; l += 4) {
      float acc = 0.f;
      for (int c = lane; c < 260; c += 64) acc += sPair[c] * a.mapL_w[l * 260 + c];
      for (int off = 32; off; off >>= 1) acc += __shfl_xor(acc, off);
      if (lane == 0) s5[l] = acc + a.mapL_b[l];
    }
    __syncthreads();
    if (vt == 0) {
      float o = a.fin_b[0];
      for (int l = 0; l < 5; ++l) o += s5[l] * a.fin_w[l];
      a.out[b] = o;
    }
  }
}

// ---------------------------------------------------------------------------
extern "C" void kernel_launch(void* const* d_in, const int* in_sizes, int n_in,
                              void* d_out, int out_size, void* d_ws, size_t ws_size,
                              hipStream_t stream) {
  Args a;
  a.z       = (const float*)d_in[0];
  a.hs_grid = (const float*)d_in[1];
  a.hs_key  = (const float*)d_in[2];
  a.lig_rep = (const float*)d_in[3];
  a.hs_rec  = (const float*)d_in[4];
  a.wRl     = (const float*)d_in[5];
  a.mask    = (const int*)d_in[6];
  a.wsrc[0] = (const float*)d_in[7];   a.wra_b = (const float*)d_in[8];
  a.wsrc[1] = (const float*)d_in[9];   a.wrh_b = (const float*)d_in[10];
  a.wsrc[2] = (const float*)d_in[11];  a.wla_b = (const float*)d_in[12];
  a.wsrc[3] = (const float*)d_in[13];  a.wlh_b = (const float*)d_in[14];
  a.z1w     = (const float*)d_in[15];
  a.wsrc[4] = (const float*)d_in[17];  // wcR_w
  a.wcR_w   = (const float*)d_in[17];
  a.wsrc[5] = (const float*)d_in[19];  a.wcl_b = (const float*)d_in[20];
  a.wsrc[6] = (const float*)d_in[21];  a.kR_b  = (const float*)d_in[22];
  a.mapL_w  = (const float*)d_in[23];  a.mapL_b = (const float*)d_in[24];
  a.fin_w   = (const float*)d_in[25];  a.fin_b  = (const float*)d_in[26];
  a.out = (float*)d_out;

  float* w = (float*)d_ws;
  a.wT    = w;                            // 7*16384
  a.ra    = a.wT + 7 * 16384;             // B*G*M
  a.att   = a.ra + Bb * Gg * Mm;          // B*G*K
  a.laNum = a.att + Bb * Gg * Kk;         // B*NCH*K*M (dead after P1)
  a.laDen = a.laNum + Bb * NCH * Kk * Mm;
  a.la    = a.laDen + Bb * NCH * Kk * Mm; // B*K*M
  a.attlP = a.la + Bb * Kk * Mm;          // 4096
  a.attrPM = a.attlP + Bb * 8 * 64;
  a.attrPS = a.attrPM + Bb * 8 * 64;
  a.att_r = a.attrPS + Bb * 8 * 64;       // B*G
  a.Lk    = a.att_r + Bb * Gg;            // B*K*M
  a.scores = a.Lk + Bb * Kk * Mm;         // B*N*K

  // aliases into laNum (dead after P1's la-reduce)
  a.pmT = a.laNum;                        // 32768
  a.psT = a.laNum + 32768;                // 32768
  a.uP  = a.laNum + 65536;                // 8192
  a.w1P = a.laNum + 73728;                // 8192
  a.w2P = a.laNum + 81920;                // 8192
  a.w0P = a.laNum + 90112;                // 64
  a.v1  = a.laNum + 90176;                // 1024
  a.v2  = a.laNum + 91200;                // 1024
  a.sAv = a.laNum + 92224;                // 8

  void* params[] = { (void*)&a };
  hipLaunchCooperativeKernel((const void*)fused, dim3(256), dim3(1024),
                             params, 0, stream);
}

// Round 7
// 88.718 us; speedup vs baseline: 2.6836x; 2.6836x over previous
//
#include <hip/hip_runtime.h>

// Problem dims
#define Bb 8
#define Gg 512
#define Kk 64
#define Nn 1024
#define Mm 128
#define KM (Kk * Mm)      // 8192
#define GPB 16            // g per block in kA z-pass
#define NCH 32            // Gg/GPB partial chunks

struct P7 { const float* p[7]; };

// ===========================================================================
// KA: z-pass (blocks 0..255) + 7x weight transpose (blocks 256..367)
//   ra[b,g,m], att[b,g,k], laNum/laDen partials per 16-g chunk
//   hs_key fragment lives in registers (constant per thread across g-loop).
// ===========================================================================
__global__ __launch_bounds__(1024) void kA(
    const float* __restrict__ z, const float* __restrict__ hs_grid,
    const float* __restrict__ hs_key, const float* __restrict__ z1w,
    P7 ptrs, float* __restrict__ wT,
    float* __restrict__ raOut, float* __restrict__ attOut,
    float* __restrict__ laNum, float* __restrict__ laDen)
{
  __shared__ __align__(16) float smem[10240];   // 41 KB
  const int bid = blockIdx.x;
  const int t = threadIdx.x;

  if (bid >= Bb * NCH) {
    // ---- weight transpose: 112 blocks, 32x32 tiles ----
    float* tile = smem;                          // 32*33
    const int r = bid - Bb * NCH;
    const int mat = r >> 4, tl = r & 15;
    const int xo = (tl & 3) * 32, y0 = (tl >> 2) * 32;
    const int tx = t & 31, ty = t >> 5;
    const float* src = ptrs.p[mat];
    float* dst = wT + (size_t)mat * Mm * Mm;
    tile[ty * 33 + tx] = src[(size_t)(y0 + ty) * Mm + xo + tx];
    __syncthreads();
    dst[(size_t)(xo + ty) * Mm + y0 + tx] = tile[tx * 33 + ty];
    return;
  }

  float* s_hsgrid = smem;            // 2048
  float* s_rn     = smem + 2048;     // 2 x 2048 (double buffered)
  float* s_rd     = smem + 6144;     // 2 x 2048

  const int b = bid >> 5;
  const int gblk = bid & 31;
  const int lane_m = t & 31;
  const int m4 = lane_m << 2;
  const int kgrp = t >> 5;           // 0..31
  const int wv = t >> 6;             // 0..15

  const float* hgb = hs_grid + ((size_t)b * Gg + gblk * GPB) * Mm;
  for (int idx = t; idx < GPB * Mm; idx += 1024) s_hsgrid[idx] = hgb[idx];

  const int ofs0 = (kgrp * 2) * Mm + m4;
  const int ofs1 = ofs0 + Mm;
  // hs_key fragment in registers — constant across the g loop
  const float4 hk0 = *reinterpret_cast<const float4*>(hs_key + (size_t)b * KM + ofs0);
  const float4 hk1 = *reinterpret_cast<const float4*>(hs_key + (size_t)b * KM + ofs1);

  const float zw0 = z1w[m4], zw1 = z1w[m4 + 1], zw2 = z1w[m4 + 2], zw3 = z1w[m4 + 3];

  float la_n[2][4], la_d[2][4];
#pragma unroll
  for (int i = 0; i < 2; ++i)
#pragma unroll
    for (int j = 0; j < 4; ++j) { la_n[i][j] = 0.f; la_d[i][j] = 0.f; }

  const float* zb = z + ((size_t)b * Gg + gblk * GPB) * (size_t)KM;
  float4 c0 = *reinterpret_cast<const float4*>(zb + ofs0);
  float4 c1 = *reinterpret_cast<const float4*>(zb + ofs1);

  __syncthreads();   // staging ready

  for (int gl = 0; gl < GPB; ++gl) {
    float4 n0 = c0, n1 = c1;
    if (gl < GPB - 1) {
      n0 = *reinterpret_cast<const float4*>(zb + (size_t)(gl + 1) * KM + ofs0);
      n1 = *reinterpret_cast<const float4*>(zb + (size_t)(gl + 1) * KM + ofs1);
    }
    const int g = gblk * GPB + gl;
    const float4 hg = *reinterpret_cast<const float4*>(s_hsgrid + gl * Mm + m4);
    float rn0 = 0, rn1 = 0, rn2 = 0, rn3 = 0, rd0 = 0, rd1 = 0, rd2 = 0, rd3 = 0;
#pragma unroll
    for (int i = 0; i < 2; ++i) {
      const float4 v = (i == 0) ? c0 : c1;
      const float4 hk = (i == 0) ? hk0 : hk1;
      const int k = kgrp * 2 + i;
      const float e0 = __expf(v.x), e1 = __expf(v.y), e2 = __expf(v.z), e3 = __expf(v.w);
      la_n[i][0] += e0 * hg.x; la_n[i][1] += e1 * hg.y; la_n[i][2] += e2 * hg.z; la_n[i][3] += e3 * hg.w;
      la_d[i][0] += e0;        la_d[i][1] += e1;        la_d[i][2] += e2;        la_d[i][3] += e3;
      rn0 += e0 * hk.x; rn1 += e1 * hk.y; rn2 += e2 * hk.z; rn3 += e3 * hk.w;
      rd0 += e0; rd1 += e1; rd2 += e2; rd3 += e3;
      float ap = v.x * zw0 + v.y * zw1 + v.z * zw2 + v.w * zw3;
      ap += __shfl_xor(ap, 16); ap += __shfl_xor(ap, 8); ap += __shfl_xor(ap, 4);
      ap += __shfl_xor(ap, 2);  ap += __shfl_xor(ap, 1);
      if (lane_m == 0) attOut[((size_t)b * Gg + g) * Kk + k] = ap;
    }
    rn0 += __shfl_xor(rn0, 32); rn1 += __shfl_xor(rn1, 32); rn2 += __shfl_xor(rn2, 32); rn3 += __shfl_xor(rn3, 32);
    rd0 += __shfl_xor(rd0, 32); rd1 += __shfl_xor(rd1, 32); rd2 += __shfl_xor(rd2, 32); rd3 += __shfl_xor(rd3, 32);
    float* rnB = s_rn + (gl & 1) * 2048;
    float* rdB = s_rd + (gl & 1) * 2048;
    if ((t & 63) < 32) {
      *reinterpret_cast<float4*>(rnB + wv * Mm + m4) = make_float4(rn0, rn1, rn2, rn3);
      *reinterpret_cast<float4*>(rdB + wv * Mm + m4) = make_float4(rd0, rd1, rd2, rd3);
    }
    __syncthreads();
    if (t < Mm) {
      float num = 0.f, den = 0.f;
#pragma unroll
      for (int ww = 0; ww < 16; ++ww) { num += rnB[ww * Mm + t]; den += rdB[ww * Mm + t]; }
      raOut[((size_t)b * Gg + g) * Mm + t] = num / den;
    }
    c0 = n0; c1 = n1;
  }

  const size_t base = ((size_t)(b * NCH + gblk)) * KM;
#pragma unroll
  for (int i = 0; i < 2; ++i) {
    const int k = kgrp * 2 + i;
    *reinterpret_cast<float4*>(laNum + base + k * Mm + m4) =
        make_float4(la_n[i][0], la_n[i][1], la_n[i][2], la_n[i][3]);
    *reinterpret_cast<float4*>(laDen + base + k * Mm + m4) =
        make_float4(la_d[i][0], la_d[i][1], la_d[i][2], la_d[i][3]);
  }
}

// ===========================================================================
// KB: [0,256) la-reduce | [256,320) att_l partials | [320,384) att_r partials
//     | [384,448) Lk chain: lh = key@wclT + bl ; Lk[k,h] = sum_m lh[k,m]*wcR[m,h]
// ===========================================================================
__global__ __launch_bounds__(256) void kB(
    const float* __restrict__ laNum, const float* __restrict__ laDen, float* __restrict__ la,
    const float* __restrict__ att, float* __restrict__ attlP,
    float* __restrict__ attrPM, float* __restrict__ attrPS,
    const float* __restrict__ hs_key, const float* __restrict__ wT,
    const float* __restrict__ wcR_w, const float* __restrict__ wcl_b,
    float* __restrict__ Lk)
{
  __shared__ __align__(16) float smem[1088];
  const int bid = blockIdx.x;
  const int t = threadIdx.x;

  if (bid < 256) {
    const int idx = bid * 256 + t;
    const int b = idx >> 13, r = idx & 8191;
    const float* np = laNum + (size_t)b * NCH * KM + r;
    const float* dp = laDen + (size_t)b * NCH * KM + r;
    float num = 0.f, den = 0.f;
#pragma unroll 8
    for (int p = 0; p < NCH; ++p) { num += np[(size_t)p * KM]; den += dp[(size_t)p * KM]; }
    la[idx] = num / den;
  } else if (bid < 320) {
    const int blk = bid - 256;
    const int b = blk >> 3, p = blk & 7;
    const int w = t >> 6, lane = t & 63;
    float acc = 0.f;
    for (int j = 0; j < 16; ++j) {
      const int g = p * 64 + w * 16 + j;
      const float a = att[((size_t)b * Gg + g) * Kk + lane];
      float mx = a;
      for (int off = 32; off; off >>= 1) mx = fmaxf(mx, __shfl_xor(mx, off));
      const float e = __expf(a - mx);
      float s = e;
      for (int off = 32; off; off >>= 1) s += __shfl_xor(s, off);
      acc += e / s;
    }
    float* sred = smem;
    sred[w * 64 + lane] = acc;
    __syncthreads();
    if (t < 64) attlP[(b * 8 + p) * 64 + t] = sred[t] + sred[64 + t] + sred[128 + t] + sred[192 + t];
  } else if (bid < 384) {
    const int blk = bid - 320;
    const int b = blk >> 3, gc = blk & 7;
    const int k = t & 63, j4 = t >> 6;
    float m = -1e30f, s = 0.f;
    for (int j = 0; j < 16; ++j) {
      const int g = gc * 64 + j4 * 16 + j;
      const float a = att[((size_t)b * Gg + g) * Kk + k];
      if (a > m) { s = s * __expf(m - a) + 1.0f; m = a; }
      else s += __expf(a - m);
    }
    float* sm = smem;          // 256
    float* ss = smem + 256;    // 256
    sm[j4 * 64 + k] = m; ss[j4 * 64 + k] = s;
    __syncthreads();
    if (t < 64) {
      float M = sm[t];
      for (int q = 1; q < 4; ++q) M = fmaxf(M, sm[q * 64 + t]);
      float S = 0.f;
      for (int q = 0; q < 4; ++q) S += ss[q * 64 + t] * __expf(sm[q * 64 + t] - M);
      attrPM[(b * 8 + gc) * 64 + t] = M;
      attrPS[(b * 8 + gc) * 64 + t] = S;
    }
  } else {
    // ---- Lk chain: 64 blocks, one per (b, 8-k tile) ----
    const int blk = bid - 384;
    const int b = blk >> 3, k8 = blk & 7;
    float* s_lh = smem;                   // 8 x 132
    const int m = t & 127;
    const int half = __builtin_amdgcn_readfirstlane(t >> 7);
    const float* wclT = wT + 5 * 16384;
    {
      const float* keyb = hs_key + ((size_t)b * Kk + k8 * 8 + half * 4) * Mm;  // wave-uniform
      float a0 = 0.f, a1 = 0.f, a2 = 0.f, a3 = 0.f;
      for (int h4 = 0; h4 < 32; ++h4) {
        const float4 r0v = *reinterpret_cast<const float4*>(keyb + h4 * 4);
        const float4 r1v = *reinterpret_cast<const float4*>(keyb + 128 + h4 * 4);
        const float4 r2v = *reinterpret_cast<const float4*>(keyb + 256 + h4 * 4);
        const float4 r3v = *reinterpret_cast<const float4*>(keyb + 384 + h4 * 4);
        const float w0 = wclT[(size_t)(h4 * 4 + 0) * Mm + m];
        const float w1 = wclT[(size_t)(h4 * 4 + 1) * Mm + m];
        const float w2 = wclT[(size_t)(h4 * 4 + 2) * Mm + m];
        const float w3 = wclT[(size_t)(h4 * 4 + 3) * Mm + m];
        a0 += r0v.x * w0 + r0v.y * w1 + r0v.z * w2 + r0v.w * w3;
        a1 += r1v.x * w0 + r1v.y * w1 + r1v.z * w2 + r1v.w * w3;
        a2 += r2v.x * w0 + r2v.y * w1 + r2v.z * w2 + r2v.w * w3;
        a3 += r3v.x * w0 + r3v.y * w1 + r3v.z * w2 + r3v.w * w3;
      }
      const float bm = wcl_b[m];
      s_lh[(half * 4 + 0) * 132 + m] = a0 + bm;
      s_lh[(half * 4 + 1) * 132 + m] = a1 + bm;
      s_lh[(half * 4 + 2) * 132 + m] = a2 + bm;
      s_lh[(half * 4 + 3) * 132 + m] = a3 + bm;
    }
    __syncthreads();
    {
      const int h = m;
      const int r0 = half * 4;
      float b0 = 0.f, b1 = 0.f, b2 = 0.f, b3 = 0.f;
      for (int mq = 0; mq < 32; ++mq) {
        const float4 L0 = *reinterpret_cast<const float4*>(&s_lh[(r0 + 0) * 132 + mq * 4]);
        const float4 L1 = *reinterpret_cast<const float4*>(&s_lh[(r0 + 1) * 132 + mq * 4]);
        const float4 L2 = *reinterpret_cast<const float4*>(&s_lh[(r0 + 2) * 132 + mq * 4]);
        const float4 L3 = *reinterpret_cast<const float4*>(&s_lh[(r0 + 3) * 132 + mq * 4]);
        const float w0 = wcR_w[(size_t)(mq * 4 + 0) * Mm + h];
        const float w1 = wcR_w[(size_t)(mq * 4 + 1) * Mm + h];
        const float w2 = wcR_w[(size_t)(mq * 4 + 2) * Mm + h];
        const float w3 = wcR_w[(size_t)(mq * 4 + 3) * Mm + h];
        b0 += L0.x * w0 + L0.y * w1 + L0.z * w2 + L0.w * w3;
        b1 += L1.x * w0 + L1.y * w1 + L1.z * w2 + L1.w * w3;
        b2 += L2.x * w0 + L2.y * w1 + L2.z * w2 + L2.w * w3;
        b3 += L3.x * w0 + L3.y * w1 + L3.z * w2 + L3.w * w3;
      }
      const size_t ob = ((size_t)b * Kk + k8 * 8 + r0) * Mm + h;
      Lk[ob] = b0; Lk[ob + Mm] = b1; Lk[ob + 2 * Mm] = b2; Lk[ob + 3 * Mm] = b3;
    }
  }
}

// ===========================================================================
// KC: [0,64) att_r final | [64,576) scores = rec @ Lk^T + softmax partials
// ===========================================================================
__global__ __launch_bounds__(256) void kC(
    const float* __restrict__ att, const float* __restrict__ attrPM, const float* __restrict__ attrPS,
    float* __restrict__ att_r,
    const float* __restrict__ hs_rec, const float* __restrict__ Lk,
    const int* __restrict__ mask, const float* __restrict__ wRl,
    float* __restrict__ scores, float* __restrict__ pmT, float* __restrict__ psT)
{
  __shared__ __align__(16) float smem[4608];
  const int bid = blockIdx.x;
  const int t = threadIdx.x;

  if (bid < 64) {
    const int b = bid >> 3, gc = bid & 7;
    const int k = t & 63, grp = t >> 6;
    float* Mx = smem;
    float* S = smem + 64;
    if (t < 64) {
      float M = -1e30f;
      for (int p = 0; p < 8; ++p) M = fmaxf(M, attrPM[(b * 8 + p) * 64 + t]);
      float s = 0.f;
      for (int p = 0; p < 8; ++p) s += attrPS[(b * 8 + p) * 64 + t] * __expf(attrPM[(b * 8 + p) * 64 + t] - M);
      Mx[t] = M; S[t] = s;
    }
    __syncthreads();
    const float Mk = Mx[k], Sk = S[k];
    for (int j = 0; j < 16; ++j) {
      const int g = gc * 64 + grp * 16 + j;
      float p = __expf(att[((size_t)b * Gg + g) * Kk + k] - Mk) / Sk;
      for (int off = 32; off; off >>= 1) p += __shfl_xor(p, off);
      if (k == 0) att_r[b * Gg + g] = p;
    }
  } else {
    const int vb = bid - 64;
    const int b = vb >> 6, ntile = vb & 63;
    const int n0 = ntile * 16;
    const int k = t & 63;
    const int hq = __builtin_amdgcn_readfirstlane(t >> 6);
    // preload this (k, hq) fragment of Lk into registers
    float rLk[32];
    {
      const float* Lp = Lk + ((size_t)b * Kk + k) * Mm + hq * 32;
#pragma unroll
      for (int j = 0; j < 8; ++j) {
        const float4 v = *reinterpret_cast<const float4*>(Lp + j * 4);
        rLk[j * 4 + 0] = v.x; rLk[j * 4 + 1] = v.y;
        rLk[j * 4 + 2] = v.z; rLk[j * 4 + 3] = v.w;
      }
    }
    float acc[16];
    const float* rb = hs_rec + ((size_t)b * Nn + n0) * Mm + hq * 32;   // wave-uniform
#pragma unroll
    for (int r = 0; r < 16; ++r) {
      const float* rp = rb + r * Mm;
      float s = 0.f;
#pragma unroll
      for (int j4 = 0; j4 < 8; ++j4) {
        const float4 rv = *reinterpret_cast<const float4*>(rp + j4 * 4);  // s_load_dwordx4
        s += rv.x * rLk[j4 * 4] + rv.y * rLk[j4 * 4 + 1] +
             rv.z * rLk[j4 * 4 + 2] + rv.w * rLk[j4 * 4 + 3];
      }
      acc[r] = s;
    }
    float* s_acc = smem;          // 4096
    float* s_m   = smem + 4096;   // 256
    float* s_s   = smem + 4352;   // 256
#pragma unroll
    for (int r = 0; r < 16; ++r) s_acc[(hq * 16 + r) * 64 + k] = acc[r];
    __syncthreads();
    const float wv = wRl[0];
    const bool msk = (mask[b * Kk + k] == 0);
    float m = -3.0e38f, ssum = 0.f;
    for (int q = 0; q < 4; ++q) {
      const int idx = q * 256 + t;
      const int r = idx >> 6, kk = idx & 63;
      float v = s_acc[r * 64 + kk] + s_acc[(16 + r) * 64 + kk] +
                s_acc[(32 + r) * 64 + kk] + s_acc[(48 + r) * 64 + kk];
      v = msk ? -1e10f : wv * v;
      scores[((size_t)b * Nn + n0 + r) * Kk + kk] = v;
      if (v > m) { ssum = ssum * __expf(m - v) + 1.0f; m = v; }
      else ssum += __expf(v - m);
    }
    s_m[hq * 64 + k] = m; s_s[hq * 64 + k] = ssum;
    __syncthreads();
    if (t < 64) {
      float M = fmaxf(fmaxf(s_m[t], s_m[64 + t]), fmaxf(s_m[128 + t], s_m[192 + t]));
      float S = 0.f;
#pragma unroll
      for (int q = 0; q < 4; ++q) S += s_s[q * 64 + t] * __expf(s_m[q * 64 + t] - M);
      pmT[((size_t)b * 64 + ntile) * 64 + t] = M;
      psT[((size_t)b * 64 + ntile) * 64 + t] = S;
    }
  }
}

// ===========================================================================
// KD: weighted-sum partial reductions (512 threads)
// ===========================================================================
__global__ __launch_bounds__(512) void kD(
    const float* __restrict__ scores, const float* __restrict__ hs_rec,
    const float* __restrict__ pmT, const float* __restrict__ psT,
    const float* __restrict__ attlP, const float* __restrict__ att_r,
    const float* __restrict__ ra, const float* __restrict__ hs_grid,
    const float* __restrict__ la, const float* __restrict__ hs_key,
    float* __restrict__ uP, float* __restrict__ w1P, float* __restrict__ w2P,
    float* __restrict__ w0P, float* __restrict__ v1, float* __restrict__ v2,
    float* __restrict__ sAv)
{
  __shared__ float sm[1280];
  __shared__ float s_attl[64];
  __shared__ float sM[64], sSi[64];
  const int bid = blockIdx.x;
  const int t = threadIdx.x;

  if (bid < 64) {
    const int b = bid >> 3, nc = bid & 7;
    if (t < 64) {
      float a = 0.f;
      for (int p = 0; p < 8; ++p) a += attlP[(b * 8 + p) * 64 + t];
      s_attl[t] = a;
      float M = -3.0e38f;
      for (int nt = 0; nt < 64; ++nt) M = fmaxf(M, pmT[((size_t)b * 64 + nt) * 64 + t]);
      float S = 0.f;
      for (int nt = 0; nt < 64; ++nt)
        S += psT[((size_t)b * 64 + nt) * 64 + t] * __expf(pmT[((size_t)b * 64 + nt) * 64 + t] - M);
      sM[t] = M; sSi[t] = 1.0f / S;
    }
    __syncthreads();
    const int n = t >> 2, ks = t & 3;
    const float* sc = scores + ((size_t)b * Nn + nc * 128 + n) * Kk + ks * 16;
    float qp = 0.f;
#pragma unroll
    for (int j = 0; j < 16; ++j) {
      const int k = ks * 16 + j;
      qp += s_attl[k] * __expf(sc[j] - sM[k]) * sSi[k];
    }
    sm[n * 4 + ks] = qp;
    __syncthreads();
    float* q = sm + 512;
    if (t < 128) q[t] = sm[t * 4] + sm[t * 4 + 1] + sm[t * 4 + 2] + sm[t * 4 + 3];
    __syncthreads();
    const int h = t & 127, nq = t >> 7;
    float acc = 0.f;
    const float* hr = hs_rec + ((size_t)b * Nn + nc * 128 + nq * 32) * Mm + h;
    for (int j = 0; j < 32; ++j) acc += q[nq * 32 + j] * hr[(size_t)j * Mm];
    float* red = sm + 640;
    red[nq * 128 + h] = acc;
    __syncthreads();
    if (t < 128) uP[((size_t)b * 8 + nc) * 128 + t] = red[t] + red[128 + t] + red[256 + t] + red[384 + t];
  } else if (bid < 128) {
    const int blk = bid - 64;
    const int b = blk >> 3, gc = blk & 7;
    float* s_ar = sm + 1152;   // 64
    if (t < 64) s_ar[t] = att_r[b * Gg + gc * 64 + t];
    __syncthreads();
    const int h = t & 127, gq = t >> 7;
    float a1 = 0.f, a2 = 0.f;
    const float* rp = ra + ((size_t)b * Gg + gc * 64 + gq * 16) * Mm + h;
    const float* gp = hs_grid + ((size_t)b * Gg + gc * 64 + gq * 16) * Mm + h;
    for (int j = 0; j < 16; ++j) {
      const float w = s_ar[gq * 16 + j];
      a1 += w * rp[(size_t)j * Mm];
      a2 += w * gp[(size_t)j * Mm];
    }
    float* r1 = sm;
    float* r2 = sm + 512;
    r1[gq * 128 + h] = a1; r2[gq * 128 + h] = a2;
    __syncthreads();
    if (t < 128) {
      w1P[((size_t)b * 8 + gc) * 128 + t] = r1[t] + r1[128 + t] + r1[256 + t] + r1[384 + t];
      w2P[((size_t)b * 8 + gc) * 128 + t] = r2[t] + r2[128 + t] + r2[256 + t] + r2[384 + t];
    }
    if (t == 0) {
      float s = 0.f;
      for (int j = 0; j < 64; ++j) s += s_ar[j];
      w0P[b * 8 + gc] = s;
    }
  } else {
    const int b = bid - 128;
    if (t < 64) {
      float a = 0.f;
      for (int p = 0; p < 8; ++p) a += attlP[(b * 8 + p) * 64 + t];
      s_attl[t] = a;
    }
    __syncthreads();
    const int h = t & 127, kq = t >> 7;
    float a1 = 0.f, a2 = 0.f;
    const float* lp = la + ((size_t)b * Kk + kq * 16) * Mm + h;
    const float* kp = hs_key + ((size_t)b * Kk + kq * 16) * Mm + h;
    for (int j = 0; j < 16; ++j) {
      const float w = s_attl[kq * 16 + j];
      a1 += w * lp[(size_t)j * Mm];
      a2 += w * kp[(size_t)j * Mm];
    }
    float* r1 = sm;
    float* r2 = sm + 512;
    r1[kq * 128 + h] = a1; r2[kq * 128 + h] = a2;
    __syncthreads();
    if (t < 128) {
      v1[b * 128 + t] = r1[t] + r1[128 + t] + r1[256 + t] + r1[384 + t];
      v2[b * 128 + t] = r2[t] + r2[128 + t] + r2[256 + t] + r2[384 + t];
    }
    if (t == 0) {
      float s = 0.f;
      for (int j = 0; j < 64; ++j) s += s_attl[j];
      sAv[b] = s;
    }
  }
}

// ===========================================================================
// KE: finale per b (1024 threads): 5 matvecs + pair -> mapL -> fin
// ===========================================================================
__global__ __launch_bounds__(1024) void kE(
    const float* __restrict__ uP, const float* __restrict__ w1P, const float* __restrict__ w2P,
    const float* __restrict__ w0P, const float* __restrict__ v1, const float* __restrict__ v2,
    const float* __restrict__ sAv, const float* __restrict__ wT,
    const float* __restrict__ wra_b, const float* __restrict__ wrh_b,
    const float* __restrict__ wla_b, const float* __restrict__ wlh_b,
    const float* __restrict__ kR_b, const float* __restrict__ lig_rep,
    const float* __restrict__ mapL_w, const float* __restrict__ mapL_b,
    const float* __restrict__ fin_w, const float* __restrict__ fin_b,
    float* __restrict__ out)
{
  __shared__ float sV1[128], sV2[128], sU[128], sW1[128], sW2[128];
  __shared__ float sPair[264];
  __shared__ float sRed[2][8][128];
  __shared__ float s5[8];
  __shared__ float sSc[2];
  const int b = blockIdx.x, t = threadIdx.x;
  const int m = t & 127, hf = t >> 7;   // hf 0..7

  if (t < 128) {
    float u = 0.f, w1 = 0.f, w2 = 0.f;
    for (int c = 0; c < 8; ++c) {
      u  += uP[((size_t)b * 8 + c) * 128 + t];
      w1 += w1P[((size_t)b * 8 + c) * 128 + t];
      w2 += w2P[((size_t)b * 8 + c) * 128 + t];
    }
    sU[t] = u; sW1[t] = w1; sW2[t] = w2;
    sV1[t] = v1[b * 128 + t]; sV2[t] = v2[b * 128 + t];
  }
  if (t == 0) {
    float s = 0.f;
    for (int c = 0; c < 8; ++c) s += w0P[b * 8 + c];
    sSc[0] = s;           // sR = sum att_r
    sSc[1] = sAv[b];      // sA = sum att_l
  }
  __syncthreads();

  const float* wraT = wT;
  const float* wrhT = wT + 1 * 16384;
  const float* wlaT = wT + 2 * 16384;
  const float* wlhT = wT + 3 * 16384;
  const float* kRT  = wT + 6 * 16384;
  float key = 0.f, grd = 0.f;
  for (int h = hf * 16; h < hf * 16 + 16; ++h) {
    key += sV1[h] * wlaT[h * Mm + m] + sV2[h] * wlhT[h * Mm + m] + sU[h] * kRT[h * Mm + m];
    grd += sW1[h] * wraT[h * Mm + m] + sW2[h] * wrhT[h * Mm + m];
  }
  sRed[0][hf][m] = key; sRed[1][hf][m] = grd;
  __syncthreads();
  if (t < 128) {
    const float sR = sSc[0], sA = sSc[1];
    float kk = 0.f, gg = 0.f;
#pragma unroll
    for (int q = 0; q < 8; ++q) { kk += sRed[0][q][t]; gg += sRed[1][q][t]; }
    sPair[t] = kk + sA * (wla_b[t] + wlh_b[t] + kR_b[t]);
    sPair[132 + t] = gg + sR * (wra_b[t] + wrh_b[t]);
  }
  if (t < 4) sPair[128 + t] = lig_rep[b * 4 + t];
  __syncthreads();

  const int wq = t >> 6, lane = t & 63;
  if (wq < 5) {
    float acc = 0.f;
    for (int c = lane; c < 260; c += 64) acc += sPair[c] * mapL_w[wq * 260 + c];
    for (int off = 32; off; off >>= 1) acc += __shfl_xor(acc, off);
    if (lane == 0) s5[wq] = acc + mapL_b[wq];
  }
  __syncthreads();
  if (t == 0) {
    float o = fin_b[0];
    for (int l = 0; l < 5; ++l) o += s5[l] * fin_w[l];
    out[b] = o;
  }
}

// ---------------------------------------------------------------------------
extern "C" void kernel_launch(void* const* d_in, const int* in_sizes, int n_in,
                              void* d_out, int out_size, void* d_ws, size_t ws_size,
                              hipStream_t stream) {
  const float* z       = (const float*)d_in[0];
  const float* hs_grid = (const float*)d_in[1];
  const float* hs_key  = (const float*)d_in[2];
  const float* lig_rep = (const float*)d_in[3];
  const float* hs_rec  = (const float*)d_in[4];
  const float* w_Rl    = (const float*)d_in[5];
  const int*   w_mask  = (const int*)d_in[6];
  const float* wra_w = (const float*)d_in[7];  const float* wra_b = (const float*)d_in[8];
  const float* wrh_w = (const float*)d_in[9];  const float* wrh_b = (const float*)d_in[10];
  const float* wla_w = (const float*)d_in[11]; const float* wla_b = (const float*)d_in[12];
  const float* wlh_w = (const float*)d_in[13]; const float* wlh_b = (const float*)d_in[14];
  const float* z1_w  = (const float*)d_in[15];
  const float* wcR_w = (const float*)d_in[17]; const float* wcR_b = (const float*)d_in[18];
  const float* wcl_w = (const float*)d_in[19]; const float* wcl_b = (const float*)d_in[20];
  const float* kR_w  = (const float*)d_in[21]; const float* kR_b  = (const float*)d_in[22];
  const float* mapL_w = (const float*)d_in[23]; const float* mapL_b = (const float*)d_in[24];
  const float* fin_w  = (const float*)d_in[25]; const float* fin_b  = (const float*)d_in[26];
  float* out = (float*)d_out;

  float* w = (float*)d_ws;
  float* wT    = w;                           // 7*16384
  float* ra    = wT + 7 * 16384;              // B*G*M = 524288
  float* att   = ra + Bb * Gg * Mm;           // B*G*K = 262144
  float* laNum = att + Bb * Gg * Kk;          // B*NCH*K*M = 2097152 (dead after kB)
  float* laDen = laNum + Bb * NCH * Kk * Mm;  // 2097152 (dead after kB)
  float* la    = laDen + Bb * NCH * Kk * Mm;  // 65536
  float* attlP = la + Bb * Kk * Mm;           // 4096
  float* attrPM = attlP + Bb * 8 * 64;        // 4096
  float* attrPS = attrPM + Bb * 8 * 64;       // 4096
  float* att_r = attrPS + Bb * 8 * 64;        // 4096
  float* Lk    = att_r + Bb * Gg;             // B*K*M = 65536
  float* scores = Lk + Bb * Kk * Mm;          // B*N*K = 524288

  // aliases into laNum (dead after kB)
  float* pmT  = laNum;                        // 32768
  float* psT  = laNum + 32768;                // 32768
  float* uP   = laNum + 65536;                // B*8*128 = 8192
  float* w1P  = laNum + 73728;                // 8192
  float* w2P  = laNum + 81920;                // 8192
  float* w0P  = laNum + 90112;                // 64
  float* v1   = laNum + 90176;                // 1024
  float* v2   = laNum + 91200;                // 1024
  float* sAv  = laNum + 92224;                // 8

  P7 ptrs;
  ptrs.p[0] = wra_w; ptrs.p[1] = wrh_w; ptrs.p[2] = wla_w; ptrs.p[3] = wlh_w;
  ptrs.p[4] = wcR_w; ptrs.p[5] = wcl_w; ptrs.p[6] = kR_w;

  kA<<<Bb * NCH + 112, 1024, 0, stream>>>(z, hs_grid, hs_key, z1_w, ptrs, wT,
                                          ra, att, laNum, laDen);
  kB<<<448, 256, 0, stream>>>(laNum, laDen, la, att, attlP, attrPM, attrPS,
                              hs_key, wT, wcR_w, wcl_b, Lk);
  kC<<<576, 256, 0, stream>>>(att, attrPM, attrPS, att_r, hs_rec, Lk,
                              w_mask, w_Rl, scores, pmT, psT);
  kD<<<136, 512, 0, stream>>>(scores, hs_rec, pmT, psT, attlP, att_r,
                              ra, hs_grid, la, hs_key,
                              uP, w1P, w2P, w0P, v1, v2, sAv);
  kE<<<Bb, 1024, 0, stream>>>(uP, w1P, w2P, w0P, v1, v2, sAv, wT,
                              wra_b, wrh_b, wla_b, wlh_b, kR_b, lig_rep,
                              mapL_w, mapL_b, fin_w, fin_b, out);
}